// Round 11
// baseline (240.167 us; speedup 1.0000x reference)
//
#include <hip/hip_runtime.h>
#include <hip/hip_bf16.h>
#include <cstddef>

#define B_SZ 2
#define SEQ  2048
#define DM   1024
#define NH   16
#define HD   64
#define LAT  256
#define MTOT (B_SZ*SEQ)   // 4096
#define LDQK 2048         // Q|K fused buffer row length
#define QSCALE 0.18033688011112042f  // 0.125 * log2(e)

typedef short bf16x8 __attribute__((ext_vector_type(8)));
typedef float floatx4 __attribute__((ext_vector_type(4)));
typedef unsigned short u16;

#if __has_builtin(__builtin_amdgcn_exp2f)
#define EXP2(x) __builtin_amdgcn_exp2f(x)
#else
#define EXP2(x) exp2f(x)
#endif

__device__ __forceinline__ u16 f2bf(float f) {
  union { float f; unsigned u; } a; a.f = f;
  unsigned r = a.u + 0x7FFFu + ((a.u >> 16) & 1u);  // RNE
  return (u16)(r >> 16);
}

__device__ __forceinline__ floatx4 mfma16(bf16x8 a, bf16x8 b, floatx4 c) {
  return __builtin_amdgcn_mfma_f32_16x16x32_bf16(a, b, c, 0, 0, 0);
}

// async global->LDS, 16B per lane
__device__ __forceinline__ void load16(const u16* g, u16* l) {
  __builtin_amdgcn_global_load_lds((const __attribute__((address_space(1))) unsigned*)g,
                                   (__attribute__((address_space(3))) unsigned*)l, 16, 0, 0);
}

// ---------------- mega prep ----------------
__device__ void transpose_tile(const float* __restrict__ W, u16* __restrict__ WT,
                               int K, int N, int k0, int n0, u16 (*t)[65]) {
  const int r = threadIdx.x >> 4;          // 0..15
  const int c4 = (threadIdx.x & 15) * 4;   // 0..60
#pragma unroll
  for (int s = 0; s < 4; s++) {
    int row = s * 16 + r;
    float4 v = *(const float4*)&W[(size_t)(k0 + row) * N + n0 + c4];
    t[row][c4 + 0] = f2bf(v.x); t[row][c4 + 1] = f2bf(v.y);
    t[row][c4 + 2] = f2bf(v.z); t[row][c4 + 3] = f2bf(v.w);
  }
  __syncthreads();
  const int r2 = threadIdx.x >> 2;          // out row = n
  const int c8 = (threadIdx.x & 3) * 16;    // out col = k
  __align__(16) u16 tmp[16];
#pragma unroll
  for (int i = 0; i < 16; i++) tmp[i] = t[c8 + i][r2];
  u16* dst = WT + (size_t)(n0 + r2) * K + k0 + c8;
  *(bf16x8*)dst       = *(const bf16x8*)&tmp[0];
  *(bf16x8*)(dst + 8) = *(const bf16x8*)&tmp[8];
}

// blocks: [0,4096) cast x | [4096,4352) Wq^T->Wbig | [4352,4416) Wku^T | [4416,4480) Wvu^T
// [4480,4736) Wo^T | [4736,4992) cast Wkd | [4992,5248) cast Wvd | [5248,5252) bq copy
// [5252,5260) combined K/V bias (dot over 256)
__global__ __launch_bounds__(256)
void prep_k(const float* __restrict__ x, u16* __restrict__ xb,
            const float* __restrict__ Wq, const float* __restrict__ Wkd,
            const float* __restrict__ Wvd, const float* __restrict__ Wku,
            const float* __restrict__ Wvu, const float* __restrict__ Wo,
            u16* __restrict__ Wbig, u16* __restrict__ WkuT,
            u16* __restrict__ WvuT, u16* __restrict__ WoT,
            u16* __restrict__ Wkd_b, u16* __restrict__ Wvd_b,
            const float* __restrict__ bq, const float* __restrict__ bkd,
            const float* __restrict__ bvd, const float* __restrict__ bku,
            const float* __restrict__ bvu, float* __restrict__ bQKV) {
  __shared__ u16 t[64][65];
  const int blk = blockIdx.x;
  if (blk < 4096) {                 // cast x
    int i = blk * 256 + threadIdx.x;
    float4 v = ((const float4*)x)[i];
    ushort4 o; o.x = f2bf(v.x); o.y = f2bf(v.y); o.z = f2bf(v.z); o.w = f2bf(v.w);
    ((ushort4*)xb)[i] = o;
  } else if (blk < 4352) {          // Wq^T -> Wbig rows [0,1024)
    int tt = blk - 4096;
    transpose_tile(Wq, Wbig, DM, DM, (tt >> 4) * 64, (tt & 15) * 64, t);
  } else if (blk < 4416) {          // Wku^T [1024][256]
    int tt = blk - 4352;
    transpose_tile(Wku, WkuT, LAT, DM, (tt & 3) * 64, (tt >> 2) * 64, t);
  } else if (blk < 4480) {          // Wvu^T
    int tt = blk - 4416;
    transpose_tile(Wvu, WvuT, LAT, DM, (tt & 3) * 64, (tt >> 2) * 64, t);
  } else if (blk < 4736) {          // Wo^T
    int tt = blk - 4480;
    transpose_tile(Wo, WoT, DM, DM, (tt >> 4) * 64, (tt & 15) * 64, t);
  } else if (blk < 4992) {          // cast Wkd (row-major = BT for combine)
    int i = (blk - 4736) * 256 + threadIdx.x;
    float4 v = ((const float4*)Wkd)[i];
    ushort4 o; o.x = f2bf(v.x); o.y = f2bf(v.y); o.z = f2bf(v.z); o.w = f2bf(v.w);
    ((ushort4*)Wkd_b)[i] = o;
  } else if (blk < 5248) {          // cast Wvd
    int i = (blk - 4992) * 256 + threadIdx.x;
    float4 v = ((const float4*)Wvd)[i];
    ushort4 o; o.x = f2bf(v.x); o.y = f2bf(v.y); o.z = f2bf(v.z); o.w = f2bf(v.w);
    ((ushort4*)Wvd_b)[i] = o;
  } else if (blk < 5252) {          // bq -> bQKV[0:1024]
    int i = (blk - 5248) * 256 + threadIdx.x;
    bQKV[i] = bq[i];
  } else {                          // combined biases: bK = bkd@Wku + bku; bV = bvd@Wvu + bvu
    int o = (blk - 5252) * 256 + threadIdx.x;   // 0..2047
    const float* bvec = (o < 1024) ? bkd : bvd;
    const float* Wup  = (o < 1024) ? Wku : Wvu;
    const float* badd = (o < 1024) ? bku : bvu;
    int n = o & 1023;
    float s = 0.f;
    for (int c = 0; c < LAT; c++) s += bvec[c] * Wup[(size_t)c * DM + n];
    bQKV[(o < 1024 ? 1024 : 2048) + n] = s + badd[n];
  }
}

// ---------------- GEMM: C = A * BT^T + bias (128x128 tile, LDS dbuf) ----------------
// VMODE=1: columns >= 2048 are V -> LDS-transposed store into Cvt[bh*64+d][s]
// (coalesced 128B runs; the scattered-8B epilogue had ~8x write amplification).
// NOTE: LDS buffers addressed as offsets into one smem array — pointer-array
// initializers of __shared__ are rejected by the gfx950 backend [R10 compile fail].
template<int OUT_BF16, int VMODE>
__global__ __launch_bounds__(256)
void gemm_bt(const u16* __restrict__ A0, const u16* __restrict__ A1,
             const u16* __restrict__ BT0, const u16* __restrict__ BT1,
             const float* __restrict__ bias0, const float* __restrict__ bias1,
             void* __restrict__ C0, void* __restrict__ C1, u16* __restrict__ Cvt,
             int M, int N, int Kd, int lda, int ldc, float qscale, int qcols) {
  __shared__ u16 smem[32768];       // As buf0|buf1 at 0/8192, Bs at 16384/24576
  const u16* A  = blockIdx.z ? A1 : A0;
  const u16* BT = blockIdx.z ? BT1 : BT0;
  const float* bias = blockIdx.z ? bias1 : bias0;
  void* C = blockIdx.z ? C1 : C0;

  const int tid = threadIdx.x;
  const int m0 = blockIdx.y * 128, n0 = blockIdx.x * 128;
  const int wave = tid >> 6, lane = tid & 63;
  const int l15 = lane & 15, quad = lane >> 4;
  const int wm = (wave >> 1) * 64, wn = (wave & 1) * 64;

  floatx4 acc[4][4];
#pragma unroll
  for (int i = 0; i < 4; i++)
#pragma unroll
    for (int j = 0; j < 4; j++) acc[i][j] = (floatx4){0.f, 0.f, 0.f, 0.f};

  const int tr = tid >> 3;
  const int tc8 = (tid & 7) * 8;
  const u16* Ag = A  + (size_t)(m0 + tr) * lda + tc8;
  const u16* Bg = BT + (size_t)(n0 + tr) * Kd + tc8;

#pragma unroll
  for (int s = 0; s < 4; s++) {
    load16(Ag + (size_t)(s * 32) * lda, &smem[tid * 8 + s * 2048]);
    load16(Bg + (size_t)(s * 32) * Kd,  &smem[16384 + tid * 8 + s * 2048]);
  }

  const int NIT = Kd >> 6;
  for (int it = 0; it < NIT; ++it) {
    const int cur = (it & 1) * 8192, nxt = cur ^ 8192;
    __syncthreads();
    if (it + 1 < NIT) {
      const int k0 = (it + 1) * 64;
#pragma unroll
      for (int s = 0; s < 4; s++) {
        load16(Ag + (size_t)(s * 32) * lda + k0, &smem[nxt + tid * 8 + s * 2048]);
        load16(Bg + (size_t)(s * 32) * Kd  + k0, &smem[16384 + nxt + tid * 8 + s * 2048]);
      }
    }
#pragma unroll
    for (int kk = 0; kk < 2; kk++) {
      bf16x8 af[4], bfr[4];
#pragma unroll
      for (int i = 0; i < 4; i++) {
        af[i]  = *(const bf16x8*)&smem[cur + (wm + i * 16 + l15) * 64 + kk * 32 + quad * 8];
        bfr[i] = *(const bf16x8*)&smem[16384 + cur + (wn + i * 16 + l15) * 64 + kk * 32 + quad * 8];
      }
#pragma unroll
      for (int i = 0; i < 4; i++)
#pragma unroll
        for (int j = 0; j < 4; j++)
          acc[i][j] = mfma16(af[i], bfr[j], acc[i][j]);
    }
  }

  if (VMODE == 1 && n0 >= 2048) {
    // ---- V columns: LDS transpose then coalesced VT store ----
    __syncthreads();                // all MFMA done; smem free
#pragma unroll
    for (int i = 0; i < 4; i++) {
      int rl = wm + i * 16 + quad * 4;
#pragma unroll
      for (int j = 0; j < 4; j++) {
        int cl = wn + j * 16 + l15;
        float bv = bias[n0 + cl];
        union { u16 u[4]; uint2 w2; } tv;
#pragma unroll
        for (int r = 0; r < 4; r++) tv.u[r] = f2bf(acc[i][j][r] + bv);
        *(uint2*)&smem[cl * 136 + rl] = tv.w2;
      }
    }
    __syncthreads();
    const int c = tid >> 1, half = tid & 1;
    const int gcol = n0 - 2048 + c;             // h*64+d
    const int bb = m0 >> 11, s0 = m0 & 2047;
    u16* dst = Cvt + ((size_t)(bb * 16 + (gcol >> 6)) * 64 + (gcol & 63)) * SEQ + s0 + half * 64;
    const u16* src = &smem[c * 136 + half * 64];
#pragma unroll
    for (int u = 0; u < 8; u++) *(bf16x8*)(dst + u * 8) = *(const bf16x8*)(src + u * 8);
  } else {
#pragma unroll
    for (int i = 0; i < 4; i++) {
      int row = m0 + wm + i * 16 + quad * 4;
#pragma unroll
      for (int j = 0; j < 4; j++) {
        int col = n0 + wn + j * 16 + l15;
        float bv = bias[col];
        float sc = (col < qcols) ? qscale : 1.f;
#pragma unroll
        for (int r = 0; r < 4; r++) {
          float v = (acc[i][j][r] + bv) * sc;
          if (OUT_BF16) ((u16*)C)[(size_t)(row + r) * ldc + col] = f2bf(v);
          else          ((float*)C)[(size_t)(row + r) * ldc + col] = v;
        }
      }
    }
  }
}

// ---------------- fused attention (R6 structure — measured 75-77 us) ----------------
// Q|K in fused QKb rows of LDQK=2048 (Q cols 0..1023 pre-scaled, K cols 1024..2047).
// DO NOT: cap VGPRs (R4 spills) / shrink q-per-wave (R7 intensity) / deepen pipeline (R8 spills).
__global__ __launch_bounds__(256, 2)
void attn_fused(const u16* __restrict__ QK, const u16* __restrict__ VT,
                u16* __restrict__ CTX) {
  __shared__ float Ocmb[64][68];
  __shared__ float Lw[4][64];
  __shared__ u16 Plds[4][64][40];
  const int bh = blockIdx.y, b = bh >> 4, h = bh & 15;
  const int wave = threadIdx.x >> 6, lane = threadIdx.x & 63;
  const int l15 = lane & 15, quad = lane >> 4;
  const int q0 = blockIdx.x * 64;

  bf16x8 qf[4][2];
  {
    const u16* Qp = QK + (size_t)(b * SEQ + q0 + l15) * LDQK + h * HD + quad * 8;
#pragma unroll
    for (int qi = 0; qi < 4; qi++)
#pragma unroll
      for (int h2 = 0; h2 < 2; h2++)
        qf[qi][h2] = *(const bf16x8*)(Qp + (size_t)qi * 16 * LDQK + h2 * 32);
  }
  const u16* Kp = QK + (size_t)(b * SEQ) * LDQK + 1024 + h * HD + quad * 8;
  const u16* Vp = VT + ((size_t)bh * HD + l15) * SEQ + quad * 8;

  floatx4 o[4][4];
#pragma unroll
  for (int dt = 0; dt < 4; dt++)
#pragma unroll
    for (int qi = 0; qi < 4; qi++) o[dt][qi] = (floatx4){0.f, 0.f, 0.f, 0.f};
  float ls[4] = {0.f, 0.f, 0.f, 0.f};

  const int kb0 = wave * 512;

  bf16x8 kfb[2][2][2], vfb[2][4];
#pragma unroll
  for (int ki = 0; ki < 2; ki++)
#pragma unroll
    for (int h2 = 0; h2 < 2; h2++)
      kfb[0][ki][h2] = *(const bf16x8*)(Kp + (size_t)(kb0 + ki * 16 + l15) * LDQK + h2 * 32);
#pragma unroll
  for (int dt = 0; dt < 4; dt++)
    vfb[0][dt] = *(const bf16x8*)(Vp + (size_t)(dt * 16) * SEQ + kb0);

#pragma unroll 2
  for (int it = 0; it < 16; ++it) {
    const int cur = it & 1, nxt = cur ^ 1;
    const int kb = kb0 + it * 32;
    if (it < 15) {
      const int kn = kb + 32;
#pragma unroll
      for (int ki = 0; ki < 2; ki++)
#pragma unroll
        for (int h2 = 0; h2 < 2; h2++)
          kfb[nxt][ki][h2] = *(const bf16x8*)(Kp + (size_t)(kn + ki * 16 + l15) * LDQK + h2 * 32);
#pragma unroll
      for (int dt = 0; dt < 4; dt++)
        vfb[nxt][dt] = *(const bf16x8*)(Vp + (size_t)(dt * 16) * SEQ + kn);
    }
    unsigned pw[4][4];
#pragma unroll
    for (int qi = 0; qi < 4; qi++) {
#pragma unroll
      for (int ki = 0; ki < 2; ki++) {
        floatx4 z = (floatx4){0.f, 0.f, 0.f, 0.f};
        z = mfma16(kfb[cur][ki][0], qf[qi][0], z);
        z = mfma16(kfb[cur][ki][1], qf[qi][1], z);
        float p0 = EXP2(z[0]), p1 = EXP2(z[1]), p2 = EXP2(z[2]), p3 = EXP2(z[3]);
        ls[qi] += (p0 + p1) + (p2 + p3);
        unsigned u0 = __float_as_uint(p0) + 0x8000u;
        unsigned u1 = __float_as_uint(p1) + 0x8000u;
        unsigned u2 = __float_as_uint(p2) + 0x8000u;
        unsigned u3 = __float_as_uint(p3) + 0x8000u;
        pw[qi][ki * 2]     = __builtin_amdgcn_perm(u1, u0, 0x07060302u);
        pw[qi][ki * 2 + 1] = __builtin_amdgcn_perm(u3, u2, 0x07060302u);
      }
    }
#pragma unroll
    for (int qi = 0; qi < 4; qi++) {
      uint2 w0; w0.x = pw[qi][0]; w0.y = pw[qi][1];
      *(uint2*)&Plds[wave][qi * 16 + l15][quad * 4] = w0;
      uint2 w1; w1.x = pw[qi][2]; w1.y = pw[qi][3];
      *(uint2*)&Plds[wave][qi * 16 + l15][16 + quad * 4] = w1;
    }
#pragma unroll
    for (int qi = 0; qi < 4; qi++) {
      bf16x8 pf = *(const bf16x8*)&Plds[wave][qi * 16 + l15][quad * 8];
#pragma unroll
      for (int dt = 0; dt < 4; dt++)
        o[dt][qi] = mfma16(vfb[cur][dt], pf, o[dt][qi]);
    }
  }

#pragma unroll
  for (int qi = 0; qi < 4; qi++) {
    float v = ls[qi];
    v += __shfl_xor(v, 16);
    v += __shfl_xor(v, 32);
    if (quad == 0) Lw[wave][qi * 16 + l15] = v;
  }
  if (wave == 0) {
#pragma unroll
    for (int dt = 0; dt < 4; dt++)
#pragma unroll
      for (int qi = 0; qi < 4; qi++)
        *(floatx4*)&Ocmb[qi * 16 + l15][dt * 16 + quad * 4] = o[dt][qi];
  }
  __syncthreads();
  if (wave == 1) {
#pragma unroll
    for (int dt = 0; dt < 4; dt++)
#pragma unroll
      for (int qi = 0; qi < 4; qi++) {
        floatx4* pp = (floatx4*)&Ocmb[qi * 16 + l15][dt * 16 + quad * 4];
        *pp = *pp + o[dt][qi];
      }
  }
  __syncthreads();
  if (wave == 2) {
#pragma unroll
    for (int dt = 0; dt < 4; dt++)
#pragma unroll
      for (int qi = 0; qi < 4; qi++) {
        floatx4* pp = (floatx4*)&Ocmb[qi * 16 + l15][dt * 16 + quad * 4];
        *pp = *pp + o[dt][qi];
      }
  }
  __syncthreads();
  if (wave == 3) {
#pragma unroll
    for (int qi = 0; qi < 4; qi++) {
      int qq = qi * 16 + l15;
      float lt = Lw[0][qq] + Lw[1][qq] + Lw[2][qq] + Lw[3][qq];
      float inv = 1.f / lt;
      u16* Crow = CTX + (size_t)(b * SEQ + q0 + qq) * DM + h * HD + quad * 4;
#pragma unroll
      for (int dt = 0; dt < 4; dt++) {
        floatx4 ov = o[dt][qi] + *(const floatx4*)&Ocmb[qq][dt * 16 + quad * 4];
        union { u16 u[4]; uint2 w2; } tv;
#pragma unroll
        for (int r = 0; r < 4; r++) tv.u[r] = f2bf(ov[r] * inv);
        *(uint2*)(Crow + dt * 16) = tv.w2;
      }
    }
  }
}

// ---------------- launch ----------------
extern "C" void kernel_launch(void* const* d_in, const int* in_sizes, int n_in,
                              void* d_out, int out_size, void* d_ws, size_t ws_size,
                              hipStream_t stream) {
  const float* x   = (const float*)d_in[0];
  const float* Wq  = (const float*)d_in[1];
  const float* bq  = (const float*)d_in[2];
  const float* Wkd = (const float*)d_in[3];
  const float* bkd = (const float*)d_in[4];
  const float* Wvd = (const float*)d_in[5];
  const float* bvd = (const float*)d_in[6];
  const float* Wku = (const float*)d_in[7];
  const float* bku = (const float*)d_in[8];
  const float* Wvu = (const float*)d_in[9];
  const float* bvu = (const float*)d_in[10];
  const float* Wo  = (const float*)d_in[11];
  const float* bo  = (const float*)d_in[12];
  float* out = (float*)d_out;

  float* bQKV  = (float*)d_ws;                      // 3072 f32
  float* zerob = bQKV + 3072;                       // 1024 f32
  u16* p = (u16*)(zerob + 1024);
  u16* xb    = p; p += (size_t)MTOT * DM;           // 8 MB
  u16* Wbig  = p; p += (size_t)3072 * DM;           // WqT | WckvT | WcvT (6 MB)
  u16* WkuT  = p; p += (size_t)DM * LAT;
  u16* WvuT  = p; p += (size_t)DM * LAT;
  u16* WoT   = p; p += (size_t)DM * DM;
  u16* Wkd_b = p; p += (size_t)DM * LAT;
  u16* Wvd_b = p; p += (size_t)DM * LAT;
  u16* QKb   = p; p += (size_t)MTOT * LDQK;         // Q(pre-scaled)|K, 16 MB
  u16* VTb   = p; p += (size_t)MTOT * DM;
  u16* CXb   = p; p += (size_t)MTOT * DM;

  hipMemsetAsync(zerob, 0, 1024 * sizeof(float), stream);

  prep_k<<<5260, 256, 0, stream>>>(x, xb, Wq, Wkd, Wvd, Wku, Wvu, Wo,
                                   Wbig, WkuT, WvuT, WoT, Wkd_b, Wvd_b,
                                   bq, bkd, bvd, bku, bvu, bQKV);

  // weight absorption: WckvT = WkuT @ Wkd^T, WcvT = WvuT @ Wvd^T  (z-merged, 128 blocks)
  gemm_bt<1, 0><<<dim3(8, 8, 2), 256, 0, stream>>>(
      WkuT, WvuT, Wkd_b, Wvd_b, zerob, zerob,
      Wbig + (size_t)1024 * DM, Wbig + (size_t)2048 * DM, nullptr,
      1024, 1024, LAT, LAT, 1024, 1.f, 0);

  // fused Q|K|V: [4096,1024]@[1024,3072], 24x32 = 768 blocks; V cols -> VTb transposed
  gemm_bt<1, 1><<<dim3(24, 32, 1), 256, 0, stream>>>(
      xb, xb, Wbig, Wbig, bQKV, bQKV, QKb, QKb, VTb,
      MTOT, 3072, DM, DM, LDQK, QSCALE, 1024);

  attn_fused<<<dim3(SEQ / 64, B_SZ * NH), 256, 0, stream>>>(QKb, VTb, CXb);

  // output projection: 8x32 = 256 blocks
  gemm_bt<0, 0><<<dim3(8, 32, 1), 256, 0, stream>>>(
      CXb, CXb, WoT, WoT, bo, bo, out, out, nullptr,
      MTOT, DM, DM, DM, DM, 1.f, 0);
}